// Round 12
// baseline (216.789 us; speedup 1.0000x reference)
//
#include <hip/hip_runtime.h>

#define Bv 32
#define Sv 128
#define Tv 2000
#define Dv 768
#define Hv 256
#define Rv 50
#define CHF 8             // frames per chunk
#define NCH 250           // chunks per batch (250*8 = 2000)
#define NB1 2000          // stage1 chunk blocks (4 chunks each)

#define FMA4(ACC, S, Q)                                   \
  ACC.x += (S) * (Q).x; ACC.y += (S) * (Q).y;             \
  ACC.z += (S) * (Q).z; ACC.w += (S) * (Q).w;

// ---------------------------------------------------------------------------
// stage1: blocks [0,2000): 8-frame chunk sums, 4 chunks/block, float4 lanes
//         blocks [2000,2256): wpad (mlp1_w K padded 250->256)
//         blocks [2256,2306): rwc[r,:] = rw[r,:256] @ aw  (arc-head fold)
//         block  2306:        rbc[r] = rw[r,:256] @ ab + rb[r]
// ---------------------------------------------------------------------------
__global__ __launch_bounds__(256) void stage1(
    const float* __restrict__ audio, const float* __restrict__ m1w,
    const float* __restrict__ rw, const float* __restrict__ aw,
    const float* __restrict__ ab, const float* __restrict__ rb,
    float* __restrict__ chunkSum, float* __restrict__ wpad,
    float* __restrict__ rwc, float* __restrict__ rbc)
{
  const int tid = threadIdx.x;
  const int blk = blockIdx.x;

  if (blk < NB1) {
    const int sub = tid >> 6, lane = tid & 63;
    const int c2 = blk * 4 + sub;
    const int b = c2 / NCH;
    const int c = c2 - b * NCH;
    const float* base = audio + ((size_t)b * Tv + (size_t)c * CHF) * Dv
                        + lane * 4;
    float4 a0{0,0,0,0}, a1{0,0,0,0}, a2{0,0,0,0};
#pragma unroll
    for (int f = 0; f < CHF; ++f) {
      const float* r = base + (size_t)f * Dv;
      const float4 u0 = *(const float4*)(r);
      const float4 u1 = *(const float4*)(r + 256);
      const float4 u2 = *(const float4*)(r + 512);
      a0.x += u0.x; a0.y += u0.y; a0.z += u0.z; a0.w += u0.w;
      a1.x += u1.x; a1.y += u1.y; a1.z += u1.z; a1.w += u1.w;
      a2.x += u2.x; a2.y += u2.y; a2.z += u2.z; a2.w += u2.w;
    }
    float* o = chunkSum + (size_t)c2 * Dv + lane * 4;
    *(float4*)(o)       = a0;
    *(float4*)(o + 256) = a1;
    *(float4*)(o + 512) = a2;
  } else if (blk < NB1 + 256) {
    const int idx = (blk - NB1) * 256 + tid;
    const int r = idx >> 8, cc = idx & 255;
    wpad[idx] = (cc < 250) ? m1w[r * 250 + cc] : 0.0f;
  } else if (blk < NB1 + 256 + Rv) {
    const int r = blk - (NB1 + 256);
    const float* rwr = rw + (size_t)r * 512;
    float acc = 0.f;
#pragma unroll 4
    for (int h = 0; h < 256; ++h)
      acc += rwr[h] * aw[(size_t)h * 256 + tid];
    rwc[(size_t)r * 256 + tid] = acc;
  } else {
    if (tid < Rv) {
      const float* rwr = rw + (size_t)tid * 512;
      float acc = rb[tid];
      for (int h = 0; h < 256; ++h) acc += rwr[h] * ab[h];
      rbc[tid] = acc;
    }
  }
}

// ---------------------------------------------------------------------------
// seg_sum (r9 version): per token, segment sum over pointer list.
// ---------------------------------------------------------------------------
__global__ __launch_bounds__(256) void seg_sum(
    const float* __restrict__ audio, const float* __restrict__ chunkSum,
    const float* __restrict__ st, const float* __restrict__ et,
    float* __restrict__ smean)
{
  const int tok = blockIdx.x;
  const int b = tok >> 7;
  const int tid = threadIdx.x;
  const int g = tid >> 6;
  const int l = tid & 63;

  __shared__ const float* plist[32];
  __shared__ float sgrp[4][768];

  const float stime = st[tok], etime = et[tok];
  const int si = (int)(stime * 50.0f);   // trunc == floor for >= 0
  const int ei = (int)(etime * 50.0f);
  const bool valid = (ei > si) && (ei <= Tv);
  const int sc = min(max(si, 0), Tv);
  const int ec = min(max(ei, 0), Tv);
  const float m = valid ? (1.0f / (float)max(ec - sc, 1)) : 0.0f;

  const float* abase = audio + (size_t)b * Tv * Dv;
  const float* csb   = chunkSum + (size_t)b * NCH * Dv;
  const int cA = (sc + CHF - 1) >> 3;
  const int cB = ec >> 3;
  int nH, nC, n;
  if (cA <= cB) {
    nH = cA * CHF - sc; nC = cB - cA; n = nH + nC + (ec - cB * CHF);
  } else {
    nH = ec - sc; nC = 0; n = nH;
  }
  if (tid < n) {
    const float* p;
    if (tid < nH)            p = abase + (size_t)(sc + tid) * Dv;
    else if (tid < nH + nC)  p = csb + (size_t)(cA + tid - nH) * Dv;
    else                     p = abase + (size_t)(cB * CHF + tid - nH - nC) * Dv;
    plist[tid] = p;
  }
  __syncthreads();

  float4 a0{0,0,0,0}, a1{0,0,0,0}, a2{0,0,0,0};
  for (int j = g; j < n; j += 4) {
    const float* p = plist[j] + l * 4;
    const float4 u0 = *(const float4*)(p);
    const float4 u1 = *(const float4*)(p + 256);
    const float4 u2 = *(const float4*)(p + 512);
    a0.x += u0.x; a0.y += u0.y; a0.z += u0.z; a0.w += u0.w;
    a1.x += u1.x; a1.y += u1.y; a1.z += u1.z; a1.w += u1.w;
    a2.x += u2.x; a2.y += u2.y; a2.z += u2.z; a2.w += u2.w;
  }
  *(float4*)&sgrp[g][l * 4]       = a0;
  *(float4*)&sgrp[g][256 + l * 4] = a1;
  *(float4*)&sgrp[g][512 + l * 4] = a2;
  __syncthreads();

  float* o = smean + (size_t)tok * Dv;
#pragma unroll
  for (int s = 0; s < 3; ++s) {
    const int d = tid + s * 256;
    o[d] = (sgrp[0][d] + sgrp[1][d] + sgrp[2][d] + sgrp[3][d]) * m;
  }
}

// ---------------------------------------------------------------------------
// tokchain helper: K=256 GEMM phase. A = 16x256 LDS tile (wave-uniform
// broadcast reads), W staged per 16-chunk via register prefetch.
// Thread (rq=tid>>6, cq=tid&63) computes rows 4rq..4rq+3 x cols 4cq..4cq+3.
// Staging: thread t owns W row (= output col) t; wv = t < N.
// ---------------------------------------------------------------------------
__device__ __forceinline__ void phase256(
    const float (*At)[264], const float* __restrict__ wrow, bool wv,
    int rq, int cq, float (*sW)[260], float4 acc[4])
{
  const int tid = rq * 64 + cq;
  const int c0 = cq * 4;
  acc[0] = float4{0,0,0,0}; acc[1] = float4{0,0,0,0};
  acc[2] = float4{0,0,0,0}; acc[3] = float4{0,0,0,0};
  float4 w0, w1, w2, w3;
  if (wv) {
    w0 = *(const float4*)(wrow);     w1 = *(const float4*)(wrow + 4);
    w2 = *(const float4*)(wrow + 8); w3 = *(const float4*)(wrow + 12);
  }
  for (int k0 = 0;;) {
    __syncthreads();
    if (wv) {
      sW[0][tid] = w0.x;  sW[1][tid] = w0.y;  sW[2][tid] = w0.z;  sW[3][tid] = w0.w;
      sW[4][tid] = w1.x;  sW[5][tid] = w1.y;  sW[6][tid] = w1.z;  sW[7][tid] = w1.w;
      sW[8][tid] = w2.x;  sW[9][tid] = w2.y;  sW[10][tid] = w2.z; sW[11][tid] = w2.w;
      sW[12][tid] = w3.x; sW[13][tid] = w3.y; sW[14][tid] = w3.z; sW[15][tid] = w3.w;
    }
    __syncthreads();
    const int kn = k0 + 16;
    if (kn < Hv && wv) {
      w0 = *(const float4*)(wrow + kn);     w1 = *(const float4*)(wrow + kn + 4);
      w2 = *(const float4*)(wrow + kn + 8); w3 = *(const float4*)(wrow + kn + 12);
    }
#pragma unroll
    for (int kq = 0; kq < 4; ++kq) {
      const float4 q0 = *(const float4*)&sW[kq * 4 + 0][c0];
      const float4 q1 = *(const float4*)&sW[kq * 4 + 1][c0];
      const float4 q2 = *(const float4*)&sW[kq * 4 + 2][c0];
      const float4 q3 = *(const float4*)&sW[kq * 4 + 3][c0];
#pragma unroll
      for (int r = 0; r < 4; ++r) {
        const float4 a = *(const float4*)&At[4 * rq + r][k0 + kq * 4];
        FMA4(acc[r], a.x, q0); FMA4(acc[r], a.y, q1);
        FMA4(acc[r], a.z, q2); FMA4(acc[r], a.w, q3);
      }
    }
    if (kn >= Hv) break;
    k0 = kn;
  }
}

// ---------------------------------------------------------------------------
// tokchain: fused proj -> mlp1 -> mlp2 -> head + rel for 16 tokens/block.
// grid = 256 blocks x 256 threads. Activations live in LDS across phases.
// ---------------------------------------------------------------------------
__global__ __launch_bounds__(256) void tokchain(
    const int* __restrict__ words, const int* __restrict__ pos_ids,
    const float* __restrict__ word_W, const float* __restrict__ pos_W,
    const float* __restrict__ smean,
    const float* __restrict__ audio_w, const float* __restrict__ audio_b,
    const float* __restrict__ wpad, const float* __restrict__ m1b,
    const float* __restrict__ m2w, const float* __restrict__ m2b,
    const float* __restrict__ aw, const float* __restrict__ ab,
    const float* __restrict__ rwc, const float* __restrict__ rbc,
    const float* __restrict__ rw,
    float* __restrict__ xfeat, float* __restrict__ head,
    float* __restrict__ relh, float* __restrict__ reld)
{
  const int row0 = blockIdx.x * 16;
  const int tid = threadIdx.x;
  const int rq = tid >> 6;         // row quad: rows 4rq..4rq+3
  const int cq = tid & 63;         // col quad: cols 4cq..4cq+3
  const int c0 = cq * 4;

  __shared__ float xt[16][264];
  __shared__ float ot[16][264];
  __shared__ float sW[16][260];
  __shared__ float sA[16][20];

  // ---- P0: embeddings into xt[:,0:150]; zero xt[:,250:256] ----
  for (int idx = tid; idx < 16 * 150; idx += 256) {
    const int r = idx / 150, c = idx - r * 150;
    const int tok = row0 + r;
    xt[r][c] = (c < 100) ? word_W[(size_t)words[tok] * 100 + c]
                         : pos_W[pos_ids[tok] * 50 + (c - 100)];
  }
  if (tid < 96) {
    xt[tid / 6][250 + (tid % 6)] = 0.0f;
  }

  float4 acc[4];

  // ---- P1: proj, out[16x100] = smean[16x768] @ audio_w[100x768]^T ----
  {
    acc[0] = float4{0,0,0,0}; acc[1] = float4{0,0,0,0};
    acc[2] = float4{0,0,0,0}; acc[3] = float4{0,0,0,0};
    const bool wv = tid < 100;
    const float* wrow = audio_w + (size_t)(wv ? tid : 0) * Dv;
    const bool av = tid < 64;
    const int ar = tid >> 2, ak = (tid & 3) * 4;
    const float* arow = smean + (size_t)(row0 + ar) * Dv + ak;
    float4 w0, w1, w2, w3, aq;
    if (wv) {
      w0 = *(const float4*)(wrow);     w1 = *(const float4*)(wrow + 4);
      w2 = *(const float4*)(wrow + 8); w3 = *(const float4*)(wrow + 12);
    }
    if (av) aq = *(const float4*)(arow);
    for (int k0 = 0;;) {
      __syncthreads();
      if (wv) {
        sW[0][tid] = w0.x;  sW[1][tid] = w0.y;  sW[2][tid] = w0.z;  sW[3][tid] = w0.w;
        sW[4][tid] = w1.x;  sW[5][tid] = w1.y;  sW[6][tid] = w1.z;  sW[7][tid] = w1.w;
        sW[8][tid] = w2.x;  sW[9][tid] = w2.y;  sW[10][tid] = w2.z; sW[11][tid] = w2.w;
        sW[12][tid] = w3.x; sW[13][tid] = w3.y; sW[14][tid] = w3.z; sW[15][tid] = w3.w;
      }
      if (av) *(float4*)&sA[ar][ak] = aq;
      __syncthreads();
      const int kn = k0 + 16;
      if (kn < Dv) {
        if (wv) {
          w0 = *(const float4*)(wrow + kn);     w1 = *(const float4*)(wrow + kn + 4);
          w2 = *(const float4*)(wrow + kn + 8); w3 = *(const float4*)(wrow + kn + 12);
        }
        if (av) aq = *(const float4*)(arow + kn);
      }
#pragma unroll
      for (int kq = 0; kq < 4; ++kq) {
        const float4 q0 = *(const float4*)&sW[kq * 4 + 0][c0];
        const float4 q1 = *(const float4*)&sW[kq * 4 + 1][c0];
        const float4 q2 = *(const float4*)&sW[kq * 4 + 2][c0];
        const float4 q3 = *(const float4*)&sW[kq * 4 + 3][c0];
#pragma unroll
        for (int r = 0; r < 4; ++r) {
          const float4 a = *(const float4*)&sA[4 * rq + r][kq * 4];
          FMA4(acc[r], a.x, q0); FMA4(acc[r], a.y, q1);
          FMA4(acc[r], a.z, q2); FMA4(acc[r], a.w, q3);
        }
      }
      if (kn >= Dv) break;
      k0 = kn;
    }
    if (c0 < 100) {
      const float4 bb = *(const float4*)&audio_b[c0];
#pragma unroll
      for (int r = 0; r < 4; ++r) {
        xt[4 * rq + r][150 + c0 + 0] = acc[r].x + bb.x;
        xt[4 * rq + r][150 + c0 + 1] = acc[r].y + bb.y;
        xt[4 * rq + r][150 + c0 + 2] = acc[r].z + bb.z;
        xt[4 * rq + r][150 + c0 + 3] = acc[r].w + bb.w;
      }
    }
  }

  // ---- P2: mlp1 = relu(xt @ wpad^T + m1b) -> ot ----
  phase256(xt, wpad + (size_t)tid * 256, true, rq, cq, sW, acc);
  {
    const float4 bb = *(const float4*)&m1b[c0];
#pragma unroll
    for (int r = 0; r < 4; ++r) {
      float4 v;
      v.x = fmaxf(acc[r].x + bb.x, 0.f); v.y = fmaxf(acc[r].y + bb.y, 0.f);
      v.z = fmaxf(acc[r].z + bb.z, 0.f); v.w = fmaxf(acc[r].w + bb.w, 0.f);
      *(float4*)&ot[4 * rq + r][c0] = v;
    }
  }

  // ---- P3: mlp2 = relu(ot @ m2w^T + m2b) -> xt (+ global xfeat) ----
  phase256(ot, m2w + (size_t)tid * 256, true, rq, cq, sW, acc);
  {
    const float4 bb = *(const float4*)&m2b[c0];
#pragma unroll
    for (int r = 0; r < 4; ++r) {
      float4 v;
      v.x = fmaxf(acc[r].x + bb.x, 0.f); v.y = fmaxf(acc[r].y + bb.y, 0.f);
      v.z = fmaxf(acc[r].z + bb.z, 0.f); v.w = fmaxf(acc[r].w + bb.w, 0.f);
      *(float4*)&xt[4 * rq + r][c0] = v;
      *(float4*)&xfeat[(size_t)(row0 + 4 * rq + r) * Hv + c0] = v;
    }
  }

  // ---- P4a: head = xt @ aw^T + ab -> global head ----
  phase256(xt, aw + (size_t)tid * 256, true, rq, cq, sW, acc);
  {
    const float4 bb = *(const float4*)&ab[c0];
#pragma unroll
    for (int r = 0; r < 4; ++r) {
      float4 v;
      v.x = acc[r].x + bb.x; v.y = acc[r].y + bb.y;
      v.z = acc[r].z + bb.z; v.w = acc[r].w + bb.w;
      *(float4*)&head[(size_t)(row0 + 4 * rq + r) * Hv + c0] = v;
    }
  }

  // ---- P4b: rel: cols 0..49 -> relh (xt @ rwc^T + rbc),
  //               cols 50..99 -> reld (xt @ rw[:,256:]^T) ----
  {
    const bool wv = tid < 100;
    const float* wrow = (tid < 50) ? (rwc + (size_t)tid * 256)
                                   : (rw + (size_t)(tid < 100 ? tid - 50 : 0) * 512 + 256);
    phase256(xt, wrow, wv, rq, cq, sW, acc);
    if (c0 < 100) {
#pragma unroll
      for (int r = 0; r < 4; ++r) {
        const int row = row0 + 4 * rq + r;
        const float av4[4] = {acc[r].x, acc[r].y, acc[r].z, acc[r].w};
#pragma unroll
        for (int j = 0; j < 4; ++j) {
          const int col = c0 + j;
          if (col < 50)       relh[(size_t)row * Rv + col] = av4[j] + rbc[col];
          else                reld[(size_t)row * Rv + (col - 50)] = av4[j];
        }
      }
    }
  }
}

// ---------------------------------------------------------------------------
// Fused scores: blocks [0,512) arc 32x32 tiles; [512,4608) rel broadcast-add.
// ---------------------------------------------------------------------------
__global__ __launch_bounds__(256) void fused_scores(
    const float* __restrict__ head, const float* __restrict__ dep,
    const float* __restrict__ relh, const float* __restrict__ reld,
    float* __restrict__ arc_out, float* __restrict__ rel_out)
{
  __shared__ float smem[6450];
  const int tid = threadIdx.x;

  if (blockIdx.x < 512) {
    const int blk = blockIdx.x;
    const int b = blk >> 4;
    const int tile = blk & 15;
    const int i0 = (tile >> 2) * 32;
    const int j0 = (tile & 3) * 32;

    float (*sh)[33] = (float(*)[33])smem;
    float (*sd)[33] = (float(*)[33])(smem + 1056);

    const int r = tid >> 3;
    const int c = (tid & 7) << 2;
    const int ty = tid >> 4;
    const int tx = tid & 15;

    float acc00 = 0.f, acc01 = 0.f, acc10 = 0.f, acc11 = 0.f;
    const float* hb = head + (size_t)(b * Sv + i0) * Hv;
    const float* db = dep + (size_t)(b * Sv + j0) * Hv;

    for (int k0 = 0; k0 < Hv; k0 += 32) {
      float4 hv = *(const float4*)(hb + (size_t)r * Hv + k0 + c);
      float4 dv = *(const float4*)(db + (size_t)r * Hv + k0 + c);
      __syncthreads();
      sh[r][c] = hv.x; sh[r][c+1] = hv.y; sh[r][c+2] = hv.z; sh[r][c+3] = hv.w;
      sd[r][c] = dv.x; sd[r][c+1] = dv.y; sd[r][c+2] = dv.z; sd[r][c+3] = dv.w;
      __syncthreads();
#pragma unroll
      for (int kk = 0; kk < 32; ++kk) {
        float h0 = sh[ty][kk],  h1 = sh[ty + 16][kk];
        float d0 = sd[tx][kk],  d1 = sd[tx + 16][kk];
        acc00 += h0 * d0; acc01 += h0 * d1;
        acc10 += h1 * d0; acc11 += h1 * d1;
      }
    }

    float* ob = arc_out + (size_t)b * Sv * Sv;
    ob[(i0 + ty) * Sv + j0 + tx]           = acc00;
    ob[(i0 + ty) * Sv + j0 + tx + 16]      = acc01;
    ob[(i0 + ty + 16) * Sv + j0 + tx]      = acc10;
    ob[(i0 + ty + 16) * Sv + j0 + tx + 16] = acc11;
  } else {
    const int bi = blockIdx.x - 512;
    const int b = bi >> 7;

    float* srd = smem;
    float* shi = smem + 6400;

    const float4* rd4 = (const float4*)(reld + (size_t)b * Sv * Rv);
    float4* s4 = (float4*)srd;
    for (int n = tid; n < (Sv * Rv / 4); n += 256) s4[n] = rd4[n];
    if (tid < Rv) shi[tid] = relh[(size_t)bi * Rv + tid];
    __syncthreads();

    float4* out4 = (float4*)(rel_out + (size_t)bi * Sv * Rv);
    const float4* srd4 = (const float4*)srd;
    for (int n = tid; n < (Sv * Rv / 4); n += 256) {
      float4 v = srd4[n];
      int r = (n * 4) % 50;
      v.x += shi[r]; r = (r == 49) ? 0 : r + 1;
      v.y += shi[r]; r = (r == 49) ? 0 : r + 1;
      v.z += shi[r]; r = (r == 49) ? 0 : r + 1;
      v.w += shi[r];
      out4[n] = v;
    }
  }
}

// ---------------------------------------------------------------------------
extern "C" void kernel_launch(void* const* d_in, const int* in_sizes, int n_in,
                              void* d_out, int out_size, void* d_ws, size_t ws_size,
                              hipStream_t stream) {
  const int*   words   = (const int*)d_in[0];
  const int*   pos_ids = (const int*)d_in[1];
  const float* audio   = (const float*)d_in[2];
  const float* st      = (const float*)d_in[3];
  const float* et      = (const float*)d_in[4];
  const float* word_W  = (const float*)d_in[5];
  const float* pos_W   = (const float*)d_in[6];
  const float* audio_w = (const float*)d_in[7];
  const float* audio_b = (const float*)d_in[8];
  const float* m1w     = (const float*)d_in[9];
  const float* m1b     = (const float*)d_in[10];
  const float* m2w     = (const float*)d_in[11];
  const float* m2b     = (const float*)d_in[12];
  const float* aw      = (const float*)d_in[13];
  const float* ab      = (const float*)d_in[14];
  const float* rw      = (const float*)d_in[15];
  const float* rb      = (const float*)d_in[16];

  float* out = (float*)d_out;
  float* ws = (float*)d_ws;

  const size_t NT = (size_t)Bv * Sv;            // 4096 tokens

  // chunkSum (24.6 MB) lives in d_out's rel region (104.8 MB) as scratch:
  // dead after seg_sum, long before fused_scores overwrites the rel region.
  // Fully rewritten by stage1 each call -> deterministic.
  float* rel_out  = out + (size_t)Bv * Sv * Sv;
  float* chunkSum = rel_out;

  float* smean = ws;                            // NT*768
  float* xfeat = smean + NT * Dv;               // NT*256 (dep)
  float* head  = xfeat + NT * 256;              // NT*256
  float* relh  = head  + NT * 256;              // NT*50
  float* reld  = relh  + NT * Rv;               // NT*50
  float* wpad  = reld  + NT * Rv;               // 256*256
  float* rwc   = wpad  + 256 * 256;             // 50*256
  float* rbc   = rwc   + Rv * 256;              // 50

  stage1<<<NB1 + 256 + Rv + 1, 256, 0, stream>>>(
      audio, m1w, rw, aw, ab, rb, chunkSum, wpad, rwc, rbc);

  seg_sum<<<(int)NT, 256, 0, stream>>>(audio, chunkSum, st, et, smean);

  tokchain<<<256, 256, 0, stream>>>(
      words, pos_ids, word_W, pos_W, smean, audio_w, audio_b,
      wpad, m1b, m2w, m2b, aw, ab, rwc, rbc, rw,
      xfeat, head, relh, reld);

  fused_scores<<<512 + (int)NT, 256, 0, stream>>>(
      head, xfeat, relh, reld, out, rel_out);
}

// Round 13
// 185.029 us; speedup vs baseline: 1.1717x; 1.1717x over previous
//
#include <hip/hip_runtime.h>

#define Bv 32
#define Sv 128
#define Tv 2000
#define Dv 768
#define Hv 256
#define Rv 50
#define CHF 8             // frames per chunk
#define NCH 250           // chunks per batch (250*8 = 2000)
#define NB1 2000          // stage1 chunk blocks (4 chunks each)

// ---------------------------------------------------------------------------
// stage1: blocks [0,2000): 8-frame chunk sums, 4 chunks/block, float4 lanes
//         blocks [2000,2256): wpad (mlp1_w K padded 250->256)
//         blocks [2256,2768): word/pos gathers into x0 (8 tokens/block)
//         blocks [2768,2818): rwc[r,:] = rw[r,:256] @ aw  (arc-head fold)
//         block  2818:        rbc[r] = rw[r,:256] @ ab + rb[r]
// ---------------------------------------------------------------------------
__global__ __launch_bounds__(256) void stage1(
    const float* __restrict__ audio, const int* __restrict__ words,
    const int* __restrict__ pos_ids, const float* __restrict__ word_W,
    const float* __restrict__ pos_W, const float* __restrict__ m1w,
    const float* __restrict__ rw, const float* __restrict__ aw,
    const float* __restrict__ ab, const float* __restrict__ rb,
    float* __restrict__ chunkSum, float* __restrict__ wpad,
    float* __restrict__ x0, float* __restrict__ rwc, float* __restrict__ rbc)
{
  const int tid = threadIdx.x;
  const int blk = blockIdx.x;

  if (blk < NB1) {
    const int sub = tid >> 6, lane = tid & 63;
    const int c2 = blk * 4 + sub;              // global chunk id 0..7999
    const int b = c2 / NCH;
    const int c = c2 - b * NCH;
    const float* base = audio + ((size_t)b * Tv + (size_t)c * CHF) * Dv
                        + lane * 4;
    float4 a0{0,0,0,0}, a1{0,0,0,0}, a2{0,0,0,0};
#pragma unroll
    for (int f = 0; f < CHF; ++f) {
      const float* r = base + (size_t)f * Dv;
      const float4 u0 = *(const float4*)(r);
      const float4 u1 = *(const float4*)(r + 256);
      const float4 u2 = *(const float4*)(r + 512);
      a0.x += u0.x; a0.y += u0.y; a0.z += u0.z; a0.w += u0.w;
      a1.x += u1.x; a1.y += u1.y; a1.z += u1.z; a1.w += u1.w;
      a2.x += u2.x; a2.y += u2.y; a2.z += u2.z; a2.w += u2.w;
    }
    float* o = chunkSum + (size_t)c2 * Dv + lane * 4;
    *(float4*)(o)       = a0;
    *(float4*)(o + 256) = a1;
    *(float4*)(o + 512) = a2;
  } else if (blk < NB1 + 256) {
    const int idx = (blk - NB1) * 256 + tid;
    const int r = idx >> 8, cc = idx & 255;
    wpad[idx] = (cc < 250) ? m1w[r * 250 + cc] : 0.0f;
  } else if (blk < NB1 + 256 + 512) {
    const int base = (blk - NB1 - 256) * 8;
#pragma unroll
    for (int rep = 0; rep < 8; ++rep) {
      const int tok = base + rep;
      if (tid < 100) {
        x0[(size_t)tok * 256 + tid] = word_W[(size_t)words[tok] * 100 + tid];
      } else if (tid < 150) {
        x0[(size_t)tok * 256 + tid] = pos_W[pos_ids[tok] * 50 + (tid - 100)];
      } else if (tid >= 250) {
        x0[(size_t)tok * 256 + tid] = 0.0f;
      }
    }
  } else if (blk < NB1 + 256 + 512 + Rv) {
    const int r = blk - (NB1 + 256 + 512);
    const float* rwr = rw + (size_t)r * 512;
    float acc = 0.f;
#pragma unroll 4
    for (int h = 0; h < 256; ++h)
      acc += rwr[h] * aw[(size_t)h * 256 + tid];
    rwc[(size_t)r * 256 + tid] = acc;
  } else {
    if (tid < Rv) {
      const float* rwr = rw + (size_t)tid * 512;
      float acc = rb[tid];
      for (int h = 0; h < 256; ++h) acc += rwr[h] * ab[h];
      rbc[tid] = acc;
    }
  }
}

// ---------------------------------------------------------------------------
// seg_sum: per token, segment sum over pointer list (head frames, chunk
// sums, tail frames; n <= 24). 4 list-entry groups x 64 lanes x 3 float4
// accs; parallel plist build; LDS tree-reduce; scale by 1/cnt on store.
// grid = 4096 tokens, block = 256.
// ---------------------------------------------------------------------------
__global__ __launch_bounds__(256) void seg_sum(
    const float* __restrict__ audio, const float* __restrict__ chunkSum,
    const float* __restrict__ st, const float* __restrict__ et,
    float* __restrict__ smean)
{
  const int tok = blockIdx.x;
  const int b = tok >> 7;
  const int tid = threadIdx.x;
  const int g = tid >> 6;          // list-entry group 0..3
  const int l = tid & 63;          // lane

  __shared__ const float* plist[32];
  __shared__ float sgrp[4][768];   // 12 KB

  const float stime = st[tok], etime = et[tok];
  const int si = (int)(stime * 50.0f);   // trunc == floor for >= 0
  const int ei = (int)(etime * 50.0f);
  const bool valid = (ei > si) && (ei <= Tv);
  const int sc = min(max(si, 0), Tv);
  const int ec = min(max(ei, 0), Tv);
  const float m = valid ? (1.0f / (float)max(ec - sc, 1)) : 0.0f;

  const float* abase = audio + (size_t)b * Tv * Dv;
  const float* csb   = chunkSum + (size_t)b * NCH * Dv;
  const int cA = (sc + CHF - 1) >> 3;    // first full chunk
  const int cB = ec >> 3;                // one past last full chunk
  int nH, nC, n;
  if (cA <= cB) {
    nH = cA * CHF - sc; nC = cB - cA; n = nH + nC + (ec - cB * CHF);
  } else {
    nH = ec - sc; nC = 0; n = nH;
  }
  // parallel plist build: thread tid owns entry tid (n <= 24 < 32)
  if (tid < n) {
    const float* p;
    if (tid < nH)            p = abase + (size_t)(sc + tid) * Dv;
    else if (tid < nH + nC)  p = csb + (size_t)(cA + tid - nH) * Dv;
    else                     p = abase + (size_t)(cB * CHF + tid - nH - nC) * Dv;
    plist[tid] = p;
  }
  __syncthreads();

  float4 a0{0,0,0,0}, a1{0,0,0,0}, a2{0,0,0,0};
  for (int j = g; j < n; j += 4) {
    const float* p = plist[j] + l * 4;
    const float4 u0 = *(const float4*)(p);
    const float4 u1 = *(const float4*)(p + 256);
    const float4 u2 = *(const float4*)(p + 512);
    a0.x += u0.x; a0.y += u0.y; a0.z += u0.z; a0.w += u0.w;
    a1.x += u1.x; a1.y += u1.y; a1.z += u1.z; a1.w += u1.w;
    a2.x += u2.x; a2.y += u2.y; a2.z += u2.z; a2.w += u2.w;
  }
  *(float4*)&sgrp[g][l * 4]       = a0;
  *(float4*)&sgrp[g][256 + l * 4] = a1;
  *(float4*)&sgrp[g][512 + l * 4] = a2;
  __syncthreads();

  float* o = smean + (size_t)tok * Dv;
#pragma unroll
  for (int s = 0; s < 3; ++s) {
    const int d = tid + s * 256;
    o[d] = (sgrp[0][d] + sgrp[1][d] + sgrp[2][d] + sgrp[3][d]) * m;
  }
}

// ---------------------------------------------------------------------------
// GEMM core: 32x64 tile, 256 threads, 2x4 acc/thread, reg-prefetch K-chunks.
// ---------------------------------------------------------------------------
template<bool BIAS, bool RELU>
__device__ __forceinline__ void gemm_core(
    const float* __restrict__ A, int lda,
    const float* __restrict__ W, int ldw,
    const float* __restrict__ bias,
    float* __restrict__ C, int ldc, int c0,
    int N, int K, int row0, int n0)
{
  __shared__ float sA[16][34];
  __shared__ float sB[16][68];

  const int tid = threadIdx.x;
  const int tm = tid >> 4;
  const int tn = tid & 15;

  float acc[2][4] = {};

  const int rowA = tid >> 2;
  const int kq = (tid & 3) << 2;
  const bool aact = tid < 128;
  const bool wval = (n0 + rowA) < N;

  const float* Ap = A + (size_t)(row0 + (rowA & 31)) * lda + kq;
  const float* Wp = W + (size_t)(wval ? (n0 + rowA) : 0) * ldw + kq;

  float4 av = float4{0, 0, 0, 0}, bv = float4{0, 0, 0, 0};
  if (aact) av = *(const float4*)Ap;
  if (wval) bv = *(const float4*)Wp;

  int k0 = 0;
  while (true) {
    __syncthreads();
    if (aact) {
      sA[kq + 0][rowA] = av.x; sA[kq + 1][rowA] = av.y;
      sA[kq + 2][rowA] = av.z; sA[kq + 3][rowA] = av.w;
    }
    sB[kq + 0][rowA] = bv.x; sB[kq + 1][rowA] = bv.y;
    sB[kq + 2][rowA] = bv.z; sB[kq + 3][rowA] = bv.w;
    __syncthreads();

    const int kn = k0 + 16;
    const bool more = kn < K;
    if (more) {
      if (aact) av = *(const float4*)(Ap + kn);
      if (wval) bv = *(const float4*)(Wp + kn);
    }

#pragma unroll
    for (int kk = 0; kk < 16; ++kk) {
      const float2 a = *(const float2*)&sA[kk][tm * 2];
      const float4 b = *(const float4*)&sB[kk][tn * 4];
      acc[0][0] += a.x * b.x; acc[0][1] += a.x * b.y;
      acc[0][2] += a.x * b.z; acc[0][3] += a.x * b.w;
      acc[1][0] += a.y * b.x; acc[1][1] += a.y * b.y;
      acc[1][2] += a.y * b.z; acc[1][3] += a.y * b.w;
    }

    if (!more) break;
    k0 = kn;
  }

#pragma unroll
  for (int i = 0; i < 2; ++i) {
    const int row = row0 + tm * 2 + i;
    float* crow = C + (size_t)row * ldc + c0;
#pragma unroll
    for (int j = 0; j < 4; ++j) {
      const int col = n0 + tn * 4 + j;
      if (col < N) {
        float v = acc[i][j];
        if (BIAS) v += bias[col];
        if (RELU) v = fmaxf(v, 0.0f);
        crow[col] = v;
      }
    }
  }
}

template<bool BIAS, bool RELU>
__global__ __launch_bounds__(256) void gemm_tn(
    const float* __restrict__ A, int lda,
    const float* __restrict__ W, int ldw,
    const float* __restrict__ bias,
    float* __restrict__ C, int ldc, int c0,
    int N, int K)
{
  gemm_core<BIAS, RELU>(A, lda, W, ldw, bias, C, ldc, c0, N, K,
                        blockIdx.x * 32, blockIdx.y * 64);
}

// ---------------------------------------------------------------------------
// heads: everything downstream of xfeat in one launch.
// ---------------------------------------------------------------------------
__global__ __launch_bounds__(256) void heads(
    const float* __restrict__ xfeat, const float* __restrict__ aw,
    const float* __restrict__ ab, const float* __restrict__ rwc,
    const float* __restrict__ rbc, const float* __restrict__ rw,
    float* __restrict__ head, float* __restrict__ relh,
    float* __restrict__ reld)
{
  const int y = blockIdx.y;
  if (y < 4)
    gemm_core<true, false>(xfeat, 256, aw, 256, ab, head, 256, 0,
                           256, 256, blockIdx.x * 32, y * 64);
  else if (y == 4)
    gemm_core<true, false>(xfeat, 256, rwc, 256, rbc, relh, 50, 0,
                           50, 256, blockIdx.x * 32, 0);
  else
    gemm_core<false, false>(xfeat, 256, rw + 256, 512, nullptr, reld, 50, 0,
                            50, 256, blockIdx.x * 32, 0);
}

// ---------------------------------------------------------------------------
// Fused scores: blocks [0,512) arc 32x32 tiles; [512,4608) rel broadcast-add
// with float4 stores.
// ---------------------------------------------------------------------------
__global__ __launch_bounds__(256) void fused_scores(
    const float* __restrict__ head, const float* __restrict__ dep,
    const float* __restrict__ relh, const float* __restrict__ reld,
    float* __restrict__ arc_out, float* __restrict__ rel_out)
{
  __shared__ float smem[6450];
  const int tid = threadIdx.x;

  if (blockIdx.x < 512) {
    const int blk = blockIdx.x;
    const int b = blk >> 4;
    const int tile = blk & 15;
    const int i0 = (tile >> 2) * 32;
    const int j0 = (tile & 3) * 32;

    float (*sh)[33] = (float(*)[33])smem;
    float (*sd)[33] = (float(*)[33])(smem + 1056);

    const int r = tid >> 3;
    const int c = (tid & 7) << 2;
    const int ty = tid >> 4;
    const int tx = tid & 15;

    float acc00 = 0.f, acc01 = 0.f, acc10 = 0.f, acc11 = 0.f;
    const float* hb = head + (size_t)(b * Sv + i0) * Hv;
    const float* db = dep + (size_t)(b * Sv + j0) * Hv;

    for (int k0 = 0; k0 < Hv; k0 += 32) {
      float4 hv = *(const float4*)(hb + (size_t)r * Hv + k0 + c);
      float4 dv = *(const float4*)(db + (size_t)r * Hv + k0 + c);
      __syncthreads();
      sh[r][c] = hv.x; sh[r][c+1] = hv.y; sh[r][c+2] = hv.z; sh[r][c+3] = hv.w;
      sd[r][c] = dv.x; sd[r][c+1] = dv.y; sd[r][c+2] = dv.z; sd[r][c+3] = dv.w;
      __syncthreads();
#pragma unroll
      for (int kk = 0; kk < 32; ++kk) {
        float h0 = sh[ty][kk],  h1 = sh[ty + 16][kk];
        float d0 = sd[tx][kk],  d1 = sd[tx + 16][kk];
        acc00 += h0 * d0; acc01 += h0 * d1;
        acc10 += h1 * d0; acc11 += h1 * d1;
      }
    }

    float* ob = arc_out + (size_t)b * Sv * Sv;
    ob[(i0 + ty) * Sv + j0 + tx]           = acc00;
    ob[(i0 + ty) * Sv + j0 + tx + 16]      = acc01;
    ob[(i0 + ty + 16) * Sv + j0 + tx]      = acc10;
    ob[(i0 + ty + 16) * Sv + j0 + tx + 16] = acc11;
  } else {
    const int bi = blockIdx.x - 512;
    const int b = bi >> 7;

    float* srd = smem;                  // reld[b]: 6400 floats
    float* shi = smem + 6400;           // relh[b,i]: 50 floats

    const float4* rd4 = (const float4*)(reld + (size_t)b * Sv * Rv);
    float4* s4 = (float4*)srd;
    for (int n = tid; n < (Sv * Rv / 4); n += 256) s4[n] = rd4[n];
    if (tid < Rv) shi[tid] = relh[(size_t)bi * Rv + tid];
    __syncthreads();

    float4* out4 = (float4*)(rel_out + (size_t)bi * Sv * Rv);
    const float4* srd4 = (const float4*)srd;
    for (int n = tid; n < (Sv * Rv / 4); n += 256) {
      float4 v = srd4[n];
      int r = (n * 4) % 50;
      v.x += shi[r]; r = (r == 49) ? 0 : r + 1;
      v.y += shi[r]; r = (r == 49) ? 0 : r + 1;
      v.z += shi[r]; r = (r == 49) ? 0 : r + 1;
      v.w += shi[r];
      out4[n] = v;
    }
  }
}

// ---------------------------------------------------------------------------
extern "C" void kernel_launch(void* const* d_in, const int* in_sizes, int n_in,
                              void* d_out, int out_size, void* d_ws, size_t ws_size,
                              hipStream_t stream) {
  const int*   words   = (const int*)d_in[0];
  const int*   pos_ids = (const int*)d_in[1];
  const float* audio   = (const float*)d_in[2];
  const float* st      = (const float*)d_in[3];
  const float* et      = (const float*)d_in[4];
  const float* word_W  = (const float*)d_in[5];
  const float* pos_W   = (const float*)d_in[6];
  const float* audio_w = (const float*)d_in[7];
  const float* audio_b = (const float*)d_in[8];
  const float* m1w     = (const float*)d_in[9];
  const float* m1b     = (const float*)d_in[10];
  const float* m2w     = (const float*)d_in[11];
  const float* m2b     = (const float*)d_in[12];
  const float* aw      = (const float*)d_in[13];
  const float* ab      = (const float*)d_in[14];
  const float* rw      = (const float*)d_in[15];
  const float* rb      = (const float*)d_in[16];

  float* out = (float*)d_out;
  float* ws = (float*)d_ws;

  const size_t NT = (size_t)Bv * Sv;            // 4096 tokens

  // chunkSum (24.6 MB) lives in d_out's rel region as scratch: dead after
  // seg_sum, long before fused_scores overwrites the rel region. Fully
  // rewritten by stage1 each call before any read -> deterministic.
  float* rel_out  = out + (size_t)Bv * Sv * Sv;
  float* chunkSum = rel_out;

  float* smean = ws;                            // NT*768
  float* x0    = smean + NT * Dv;               // NT*256
  float* h1    = x0    + NT * 256;              // NT*256
  float* xfeat = h1    + NT * 256;              // NT*256 (dep)
  float* head  = xfeat + NT * 256;              // NT*256
  float* relh  = head  + NT * 256;              // NT*50
  float* reld  = relh  + NT * Rv;               // NT*50
  float* wpad  = reld  + NT * Rv;               // 256*256
  float* rwc   = wpad  + 256 * 256;             // 50*256
  float* rbc   = rwc   + Rv * 256;              // 50

  stage1<<<NB1 + 256 + 512 + Rv + 1, 256, 0, stream>>>(
      audio, words, pos_ids, word_W, pos_W, m1w, rw, aw, ab, rb,
      chunkSum, wpad, x0, rwc, rbc);

  seg_sum<<<(int)NT, 256, 0, stream>>>(audio, chunkSum, st, et, smean);

  // audio projection: x0[:, 150:250] = smean @ audio_w.T + audio_b
  gemm_tn<true, false><<<dim3(128, 2), 256, 0, stream>>>(
      smean, Dv, audio_w, Dv, audio_b, x0, 256, 150, 100, Dv);

  // mlp1: h1 = relu(x0 @ wpad.T + m1b)
  gemm_tn<true, true><<<dim3(128, 4), 256, 0, stream>>>(
      x0, 256, wpad, 256, m1b, h1, 256, 0, 256, 256);

  // mlp2: xfeat = relu(h1 @ m2w.T + m2b)
  gemm_tn<true, true><<<dim3(128, 4), 256, 0, stream>>>(
      h1, 256, m2w, 256, m2b, xfeat, 256, 0, 256, 256);

  // head / relh / reld in one launch
  heads<<<dim3(128, 6), 256, 0, stream>>>(
      xfeat, aw, ab, rwc, rbc, rw, head, relh, reld);

  fused_scores<<<512 + (int)NT, 256, 0, stream>>>(
      head, xfeat, relh, reld, out, rel_out);
}